// Round 3
// baseline (4040.099 us; speedup 1.0000x reference)
//
#include <hip/hip_runtime.h>
#include <math.h>

#define NROWS 65536   // 8192 tokens * 8 codebooks
#define NTOK  8192
#define NKEY  2048

// ======================= LN row stats (f64) =======================
__global__ __launch_bounds__(256) void ln_stats_k(const float* __restrict__ X,
                                                  double* __restrict__ mu,
                                                  double* __restrict__ rstd,
                                                  int nrows)
{
    int lane = threadIdx.x & 63;
    int wid  = (int)((blockIdx.x * blockDim.x + threadIdx.x) >> 6);
    if (wid >= nrows) return;
    float4 v = reinterpret_cast<const float4*>(X + (size_t)wid * 256)[lane];
    double s  = (double)v.x + v.y + v.z + v.w;
    double ss = (double)v.x*v.x + (double)v.y*v.y + (double)v.z*v.z + (double)v.w*v.w;
    #pragma unroll
    for (int off = 32; off >= 1; off >>= 1) {
        s  += __shfl_xor(s, off);
        ss += __shfl_xor(ss, off);
    }
    if (lane == 0) {
        double m   = s * (1.0/256.0);
        double var = ss * (1.0/256.0) - m*m;
        mu[wid]   = m;
        rstd[wid] = 1.0 / sqrt(var + 1e-5);
    }
}

// ======================= row sum of squares (f32, screening only) =======================
__global__ __launch_bounds__(256) void rowsq_k(const float* __restrict__ X,
                                               float* __restrict__ out, int nrows)
{
    int lane = threadIdx.x & 63;
    int wid  = (int)((blockIdx.x * blockDim.x + threadIdx.x) >> 6);
    if (wid >= nrows) return;
    float4 v = reinterpret_cast<const float4*>(X + (size_t)wid * 256)[lane];
    float ss = v.x*v.x + v.y*v.y + v.z*v.z + v.w*v.w;
    #pragma unroll
    for (int off = 32; off >= 1; off >>= 1) ss += __shfl_xor(ss, off);
    if (lane == 0) out[wid] = ss;
}

// ======================= generic GEMM, f64 accumulate =======================
// Out(f32) = post(A' @ W^T + bias); A: M x 256, W: N x 256 row-major
template<bool LN, bool GELU_ACT, bool RES, bool PERM>
__global__ __launch_bounds__(256) void gemm_k(
    const float* __restrict__ A, const float* __restrict__ W,
    const float* __restrict__ bias,
    const double* __restrict__ mu, const double* __restrict__ rstd,
    const float* __restrict__ lg, const float* __restrict__ lb,
    const float* __restrict__ R,
    float* __restrict__ Out, int N)
{
    __shared__ float As[64][68];
    __shared__ float Bs[64][68];
    const int tid  = threadIdx.x;
    const int row0 = blockIdx.x * 64;
    const int col0 = blockIdx.y * 64;
    const int ty = tid >> 4, tx = tid & 15;
    double acc[4][4] = {};

    for (int kt = 0; kt < 4; ++kt) {
        if (kt) __syncthreads();
        #pragma unroll
        for (int i = 0; i < 4; ++i) {
            int i4 = i*256 + tid;
            int r = i4 >> 4, c4 = i4 & 15;
            float4 v = *reinterpret_cast<const float4*>(A + (size_t)(row0 + r)*256 + kt*64 + c4*4);
            if constexpr (LN) {
                double m = mu[row0 + r], rs = rstd[row0 + r];
                int db = kt*64 + c4*4;
                v.x = (float)(((double)v.x - m)*rs*(double)lg[db+0] + (double)lb[db+0]);
                v.y = (float)(((double)v.y - m)*rs*(double)lg[db+1] + (double)lb[db+1]);
                v.z = (float)(((double)v.z - m)*rs*(double)lg[db+2] + (double)lb[db+2]);
                v.w = (float)(((double)v.w - m)*rs*(double)lg[db+3] + (double)lb[db+3]);
            }
            *reinterpret_cast<float4*>(&As[r][c4*4]) = v;
        }
        #pragma unroll
        for (int i = 0; i < 4; ++i) {
            int i4 = i*256 + tid;
            int r = i4 >> 4, c4 = i4 & 15;
            float4 v = *reinterpret_cast<const float4*>(W + (size_t)(col0 + r)*256 + kt*64 + c4*4);
            Bs[c4*4+0][r] = v.x; Bs[c4*4+1][r] = v.y;
            Bs[c4*4+2][r] = v.z; Bs[c4*4+3][r] = v.w;
        }
        __syncthreads();
        for (int kk = 0; kk < 64; kk += 4) {
            float aa[4][4], bb[4][4];
            #pragma unroll
            for (int i = 0; i < 4; ++i)
                *reinterpret_cast<float4*>(aa[i]) = *reinterpret_cast<const float4*>(&As[ty*4+i][kk]);
            #pragma unroll
            for (int s = 0; s < 4; ++s)
                *reinterpret_cast<float4*>(bb[s]) = *reinterpret_cast<const float4*>(&Bs[kk+s][tx*4]);
            double da[4][4], db_[4][4];
            #pragma unroll
            for (int i = 0; i < 4; ++i)
                #pragma unroll
                for (int s = 0; s < 4; ++s) { da[i][s] = (double)aa[i][s]; db_[s][i] = (double)bb[s][i]; }
            #pragma unroll
            for (int i = 0; i < 4; ++i)
                #pragma unroll
                for (int j = 0; j < 4; ++j)
                    acc[i][j] = fma(da[i][0], db_[0][j],
                                fma(da[i][1], db_[1][j],
                                fma(da[i][2], db_[2][j],
                                fma(da[i][3], db_[3][j], acc[i][j]))));
        }
    }

    #pragma unroll
    for (int i = 0; i < 4; ++i) {
        int r = row0 + ty*4 + i;
        #pragma unroll
        for (int j = 0; j < 4; ++j) {
            int cc = col0 + tx*4 + j;
            double v = acc[i][j] + (double)bias[cc];
            if constexpr (GELU_ACT) v = 0.5 * v * (1.0 + erf(v * 0.7071067811865476));
            if constexpr (RES) v += (double)R[(size_t)r * N + cc];
            size_t oi;
            if constexpr (PERM) { int c8 = r & 7; int bb2 = r >> 3; oi = ((size_t)c8*8192 + bb2)*256 + cc; }
            else oi = (size_t)r * N + cc;
            Out[oi] = (float)v;
        }
    }
}

// ======================= per-token 8x8 attention (f64 internal) =======================
__global__ __launch_bounds__(256) void attn_k(const float* __restrict__ qkv,
                                              float* __restrict__ o)
{
    __shared__ float  sq[4][8*772];
    __shared__ double sa[4][128];
    const int wv = threadIdx.x >> 6, lane = threadIdx.x & 63;
    const int tok = blockIdx.x * 4 + wv;
    float* dst = sq[wv];
    const float* src = qkv + (size_t)tok * 6144;
    #pragma unroll
    for (int i = 0; i < 24; ++i) {
        int i4  = i*64 + lane;
        int row = i4 / 192;
        int off = i4 % 192;
        float4 v = reinterpret_cast<const float4*>(src)[i4];
        *reinterpret_cast<float4*>(&dst[row*772 + off*4]) = v;
    }
    __syncthreads();
    const int l = lane >> 3, m = lane & 7;
    #pragma unroll
    for (int hh = 0; hh < 2; ++hh) {
        double s = 0.0;
        const float* qp = dst + l*772 + hh*128;
        const float* kp = dst + m*772 + 256 + hh*128;
        #pragma unroll 8
        for (int d = 0; d < 128; ++d) s = fma((double)qp[d], (double)kp[d], s);
        s *= 0.08838834764831843876;   // 1/sqrt(128)
        double mx = s;
        mx = fmax(mx, __shfl_xor(mx, 1));
        mx = fmax(mx, __shfl_xor(mx, 2));
        mx = fmax(mx, __shfl_xor(mx, 4));
        double e = exp(s - mx);
        double sum = e;
        sum += __shfl_xor(sum, 1);
        sum += __shfl_xor(sum, 2);
        sum += __shfl_xor(sum, 4);
        sa[wv][hh*64 + l*8 + m] = e / sum;
    }
    __syncthreads();
    #pragma unroll
    for (int i = 0; i < 32; ++i) {
        int idx = i*64 + lane;
        int ll = idx >> 8, d = idx & 255;
        int hh = d >> 7;
        double acc = 0.0;
        #pragma unroll
        for (int mm = 0; mm < 8; ++mm)
            acc = fma(sa[wv][hh*64 + ll*8 + mm], (double)dst[mm*772 + 512 + d], acc);
        o[(size_t)(tok*8 + ll)*256 + d] = (float)acc;
    }
}

// ======================= dist screening + top-6 candidates =======================
__global__ __launch_bounds__(256) void dist_topk_k(
    const float* __restrict__ flat,
    const float* __restrict__ keys,
    const float* __restrict__ ksq,
    int* __restrict__ cand)
{
    __shared__ float fl[64][260];
    __shared__ float kt[64][260];
    const int tid = threadIdx.x;
    const int c   = blockIdx.y;
    const int b0  = blockIdx.x * 64;
    const int ty = tid >> 4, tx = tid & 15;

    #pragma unroll
    for (int i = 0; i < 16; ++i) {
        int i4 = i*256 + tid;
        int r = i4 >> 6, c4 = i4 & 63;
        float4 v = *reinterpret_cast<const float4*>(flat + ((size_t)c*8192 + b0 + r)*256 + c4*4);
        *reinterpret_cast<float4*>(&fl[r][c4*4]) = v;
    }

    float tv[4][4]; int tix[4][4];
    #pragma unroll
    for (int i = 0; i < 4; ++i)
        #pragma unroll
        for (int t = 0; t < 4; ++t) { tv[i][t] = -INFINITY; tix[i][t] = 0; }

    int swz[4];
    #pragma unroll
    for (int q = 0; q < 4; ++q) { int rr = tx*4+q; swz[q] = ((rr >> 3) & 7) << 2; }

    for (int ktile = 0; ktile < 32; ++ktile) {
        __syncthreads();
        #pragma unroll
        for (int i = 0; i < 16; ++i) {
            int i4 = i*256 + tid;
            int r = i4 >> 6, c4 = i4 & 63;
            float4 v = *reinterpret_cast<const float4*>(keys + ((size_t)c*2048 + ktile*64 + r)*256 + c4*4);
            int col = (c4*4) ^ (((r >> 3) & 7) << 2);
            *reinterpret_cast<float4*>(&kt[r][col]) = v;
        }
        __syncthreads();
        float acc[4][4] = {};
        #pragma unroll 2
        for (int d = 0; d < 256; d += 4) {
            float aa[4][4], bb[4][4];
            #pragma unroll
            for (int i = 0; i < 4; ++i)
                *reinterpret_cast<float4*>(aa[i]) = *reinterpret_cast<const float4*>(&fl[ty*4+i][d]);
            #pragma unroll
            for (int q = 0; q < 4; ++q)
                *reinterpret_cast<float4*>(bb[q]) = *reinterpret_cast<const float4*>(&kt[tx*4+q][d ^ swz[q]]);
            #pragma unroll
            for (int i = 0; i < 4; ++i)
                #pragma unroll
                for (int q = 0; q < 4; ++q)
                    acc[i][q] = fmaf(aa[i][0], bb[q][0],
                                fmaf(aa[i][1], bb[q][1],
                                fmaf(aa[i][2], bb[q][2],
                                fmaf(aa[i][3], bb[q][3], acc[i][q]))));
        }
        #pragma unroll
        for (int q = 0; q < 4; ++q) {
            int j = ktile*64 + tx*4 + q;
            float kq = ksq[c*2048 + j];
            #pragma unroll
            for (int i = 0; i < 4; ++i) {
                float dv = fmaf(2.f, acc[i][q], -kq);
                if (dv > tv[i][3]) {
                    bool g0 = dv > tv[i][0], g1 = dv > tv[i][1], g2 = dv > tv[i][2];
                    if (g0) {
                        tv[i][3]=tv[i][2]; tix[i][3]=tix[i][2];
                        tv[i][2]=tv[i][1]; tix[i][2]=tix[i][1];
                        tv[i][1]=tv[i][0]; tix[i][1]=tix[i][0];
                        tv[i][0]=dv; tix[i][0]=j;
                    } else if (g1) {
                        tv[i][3]=tv[i][2]; tix[i][3]=tix[i][2];
                        tv[i][2]=tv[i][1]; tix[i][2]=tix[i][1];
                        tv[i][1]=dv; tix[i][1]=j;
                    } else if (g2) {
                        tv[i][3]=tv[i][2]; tix[i][3]=tix[i][2];
                        tv[i][2]=dv; tix[i][2]=j;
                    } else {
                        tv[i][3]=dv; tix[i][3]=j;
                    }
                }
            }
        }
    }

    __syncthreads();
    float* candv = &fl[0][0];
    int*   candi = reinterpret_cast<int*>(&kt[0][0]);
    #pragma unroll
    for (int i = 0; i < 4; ++i)
        #pragma unroll
        for (int t = 0; t < 4; ++t) {
            candv[((ty*4+i)*16 + tx)*4 + t] = tv[i][t];
            candi[((ty*4+i)*16 + tx)*4 + t] = tix[i][t];
        }
    __syncthreads();
    if (tid < 64) {
        int rr = tid;
        float* cv = &candv[rr*64];
        int*   ci = &candi[rr*64];
        size_t cb = ((size_t)c*8192 + b0 + rr)*8;
        #pragma unroll
        for (int t = 0; t < 6; ++t) {
            float best = -INFINITY; int besti = 0x7fffffff; int bestp = 0;
            for (int p = 0; p < 64; ++p) {
                float v = cv[p]; int ix = ci[p];
                if (v > best || (v == best && ix < besti)) { best = v; besti = ix; bestp = p; }
            }
            cv[bestp] = -INFINITY;
            cand[cb + t] = besti;
        }
    }
}

// ======================= finalize: exact f64 rescore + top-4 + gather =======================
__global__ __launch_bounds__(256) void finalize_k(
    const float* __restrict__ flat,
    const float* __restrict__ keys, const float* __restrict__ values,
    const float* __restrict__ counter,
    const int* __restrict__ cand,
    float* __restrict__ out_qv, float* __restrict__ out_qk,
    float* __restrict__ out_ind, float* __restrict__ out_dist, float* __restrict__ out_cnt)
{
    const int bid = blockIdx.x;          // c*8192 + b
    const int c = bid >> 13, b = bid & 8191;
    __shared__ double sd[8];
    __shared__ int    si[8];
    __shared__ int    sel[4];
    const int wv = threadIdx.x >> 6, lane = threadIdx.x & 63;
    const float4 fv = reinterpret_cast<const float4*>(flat + ((size_t)c*8192 + b)*256)[lane];
    for (int t = wv; t < 6; t += 4) {
        int idx = cand[(size_t)bid*8 + t];
        const float4 kv = reinterpret_cast<const float4*>(keys + ((size_t)c*2048 + idx)*256)[lane];
        double d0 = (double)fv.x - (double)kv.x;
        double d1 = (double)fv.y - (double)kv.y;
        double d2 = (double)fv.z - (double)kv.z;
        double d3 = (double)fv.w - (double)kv.w;
        double s = d0*d0 + d1*d1 + d2*d2 + d3*d3;
        #pragma unroll
        for (int off = 32; off >= 1; off >>= 1) s += __shfl_xor(s, off);
        if (lane == 0) { sd[t] = -s; si[t] = idx; }
    }
    __syncthreads();
    if (threadIdx.x == 0) {
        bool used[6] = {false,false,false,false,false,false};
        size_t obase = ((size_t)b*8 + c)*4;
        #pragma unroll
        for (int t = 0; t < 4; ++t) {
            double best = -INFINITY; int besti = 0x7fffffff; int bestp = 0;
            for (int p = 0; p < 6; ++p) {
                if (used[p]) continue;
                double v = sd[p]; int ix = si[p];
                if (v > best || (v == best && ix < besti)) { best = v; besti = ix; bestp = p; }
            }
            used[bestp] = true;
            sel[t] = besti;
            out_ind[obase + t]  = (float)besti;
            out_dist[obase + t] = (float)best;
            out_cnt[obase + t]  = counter[c*2048 + besti];
        }
    }
    __syncthreads();
    int idx = sel[wv];
    size_t src = ((size_t)c*2048 + idx)*256 + lane*4;
    size_t dst = ((((size_t)b*8 + c)*4 + wv)*256) + lane*4;
    *reinterpret_cast<float4*>(out_qv + dst) = *reinterpret_cast<const float4*>(values + src);
    *reinterpret_cast<float4*>(out_qk + dst) = *reinterpret_cast<const float4*>(keys + src);
}

// ======================= launch =======================
extern "C" void kernel_launch(void* const* d_in, const int* in_sizes, int n_in,
                              void* d_out, int out_size, void* d_ws, size_t ws_size,
                              hipStream_t stream)
{
    (void)in_sizes; (void)n_in; (void)out_size; (void)ws_size;
    const float* x       = (const float*)d_in[0];
    const float* keys    = (const float*)d_in[1];
    const float* values  = (const float*)d_in[2];
    const float* counter = (const float*)d_in[3];
    const float* ln1_g   = (const float*)d_in[4];
    const float* ln1_b   = (const float*)d_in[5];
    const float* w_in    = (const float*)d_in[6];
    const float* b_in    = (const float*)d_in[7];
    const float* w_out   = (const float*)d_in[8];
    const float* b_out   = (const float*)d_in[9];
    const float* ln2_g   = (const float*)d_in[10];
    const float* ln2_b   = (const float*)d_in[11];
    const float* ffn_w1  = (const float*)d_in[12];
    const float* ffn_b1  = (const float*)d_in[13];
    const float* ffn_w2  = (const float*)d_in[14];
    const float* ffn_b2  = (const float*)d_in[15];
    const float* dec_w   = (const float*)d_in[16];
    const float* dec_b   = (const float*)d_in[17];

    float* out = (float*)d_out;
    float* out_qv   = out;
    float* out_qk   = out + 67108864ULL;
    float* out_ind  = out + 134217728ULL;
    float* out_dist = out + 134479872ULL;
    float* out_cnt  = out + 134742016ULL;
    float* out_flat = out + 135004160ULL;

    float* ws    = (float*)d_ws;
    float* qkv   = ws;                       // [0, 50331648)
    float* h     = ws;                       // [0, 16777216)   (reuse: qkv dead after attn)
    float* f1    = ws + 16777216ULL;         // [16777216, 33554432)
    float* h2    = ws + 33554432ULL;         // [33554432, 50331648)
    float* o_buf = ws + 50331648ULL;         // [50331648, 67108864)
    double* mu1   = (double*)(ws + 67108864ULL);
    double* rstd1 = mu1 + 65536;
    double* mu2   = rstd1 + 65536;
    double* rstd2 = mu2 + 65536;
    float*  ksq   = ws + 67108864ULL + 524288ULL;        // 16384 floats
    int*    cand  = (int*)(ws + 67108864ULL + 524288ULL + 16384ULL);  // 524288 ints

    // 1) LN1 stats
    ln_stats_k<<<dim3(NROWS/4), 256, 0, stream>>>(x, mu1, rstd1, NROWS);
    // 2) qkv = LN1(x) @ w_in^T + b_in
    gemm_k<true,false,false,false><<<dim3(1024,12), 256, 0, stream>>>(
        x, w_in, b_in, mu1, rstd1, ln1_g, ln1_b, nullptr, qkv, 768);
    // 3) attention
    attn_k<<<dim3(NTOK/4), 256, 0, stream>>>(qkv, o_buf);
    // 4) h = o @ w_out^T + b_out + x
    gemm_k<false,false,true,false><<<dim3(1024,4), 256, 0, stream>>>(
        o_buf, w_out, b_out, nullptr, nullptr, nullptr, nullptr, x, h, 256);
    // 5) LN2 stats
    ln_stats_k<<<dim3(NROWS/4), 256, 0, stream>>>(h, mu2, rstd2, NROWS);
    // 6) f1 = gelu(LN2(h) @ ffn_w1^T + b1)
    gemm_k<true,true,false,false><<<dim3(1024,4), 256, 0, stream>>>(
        h, ffn_w1, ffn_b1, mu2, rstd2, ln2_g, ln2_b, nullptr, f1, 256);
    // 7) h2 = f1 @ ffn_w2^T + b2 + h
    gemm_k<false,false,true,false><<<dim3(1024,4), 256, 0, stream>>>(
        f1, ffn_w2, ffn_b2, nullptr, nullptr, nullptr, nullptr, h, h2, 256);
    // 8) flatten = h2 @ dec_w^T + dec_b  (permuted to (c, bn, 256))
    gemm_k<false,false,false,true><<<dim3(1024,4), 256, 0, stream>>>(
        h2, dec_w, dec_b, nullptr, nullptr, nullptr, nullptr, nullptr, out_flat, 256);
    // 9) key row norms (screening only)
    rowsq_k<<<dim3(16384/4), 256, 0, stream>>>(keys, ksq, 16384);
    // 10) screening dist + top-6 candidates
    dist_topk_k<<<dim3(NTOK/64, 8), 256, 0, stream>>>(out_flat, keys, ksq, cand);
    // 11) exact f64 rescore + final top-4 + outputs + gathers
    finalize_k<<<dim3(NROWS), 256, 0, stream>>>(
        out_flat, keys, values, counter, cand,
        out_qv, out_qk, out_ind, out_dist, out_cnt);
}